// Round 20
// baseline (1455.562 us; speedup 1.0000x reference)
//
#include <hip/hip_runtime.h>

#define TT 512
#define HH 256

typedef _Float16 half2t __attribute__((ext_vector_type(2)));

// fp16-pair dot with fp32 accumulate (v_dot2_f32_f16 when available).
__device__ __forceinline__ float dot2acc(unsigned w, unsigned h, float acc) {
#if __has_builtin(__builtin_amdgcn_fdot2)
    return __builtin_amdgcn_fdot2(__builtin_bit_cast(half2t, w),
                                  __builtin_bit_cast(half2t, h), acc, false);
#else
    union U { unsigned u; _Float16 f[2]; };
    U uw, uh; uw.u = w; uh.u = h;
    acc = __builtin_fmaf((float)uw.f[0], (float)uh.f[0], acc);
    acc = __builtin_fmaf((float)uw.f[1], (float)uh.f[1], acc);
    return acc;
#endif
}

__device__ __forceinline__ unsigned packh2(float a, float b) {
    union U { _Float16 f[2]; unsigned u; } r;
    r.f[0] = (_Float16)a; r.f[1] = (_Float16)b;   // RNE conversion
    return r.u;
}

#define AGPR_W(dst, src) \
    asm volatile("v_accvgpr_write_b32 %0, %1" : "=a"(dst) : "v"(src))
#define AGPR_R(dst, src) \
    asm("v_accvgpr_read_b32 %0, %1" : "=v"(dst) : "a"(src))

// uniform h word k via cross-lane read (no LDS, no memory latency)
#define HLANE(src, k) \
    ((unsigned)__builtin_amdgcn_readlane((int)(src), (k)))

// C=1, 1024 threads/wg, one wg per batch (128 wgs, plain launch).
// Thread j owns gate-row j: 128 packed fp16 words = 64 AGPR + 28 arch +
// 36 LDS tail. 16 waves = 4 waves/SIMD; budget 128 = 64 arch + 64 AGPR.
//
// R20 change: h consumed via READLANE, not LDS broadcast. Lane l reads h
// words l and 64+l (two ds_read_b32/step, conflict-free); each h word is
// then a latency-free __builtin_amdgcn_readlane feeding dot2's wave-uniform
// operand. R15-R19's 32 broadcast ds_read_b128/wave/step (the latency +
// LDS-issue bottleneck; VALUBusy pinned at 31-33%) are gone; dot is now a
// pure VALU stream with only the 9 tail b128 reads on the LDS pipe.
__global__ __launch_bounds__(1024)
__attribute__((amdgpu_waves_per_eu(4, 4)))
void lstm_single(
    const float* __restrict__ x,      // [B,T]
    const float* __restrict__ W_ih,   // [1024]
    const float* __restrict__ W_hh,   // [1024,256]
    const float* __restrict__ b_ih,   // [1024]
    const float* __restrict__ b_hh,   // [1024]
    const float* __restrict__ W1,     // [128,256]
    const float* __restrict__ b1,     // [128]
    const float* __restrict__ W2,     // [128]
    const float* __restrict__ b2,     // [1]
    float* __restrict__ out)          // [B]
{
    const int b = blockIdx.x;
    const int j = threadIdx.x;        // 0..1023 = gate-row
    const int lane = j & 63;

    __shared__ unsigned wl[9][1024][4];   // 144 KB: LDS weight tail (words 92..127)
    __shared__ unsigned h_lds[128];       // 512 B: h as fp16 pairs
    __shared__ float    h32[HH];          // 1 KB: h fp32 (epilogue)
    __shared__ float    gates[1024];      // 4 KB
    __shared__ float    x_lds[TT];        // 2 KB
    __shared__ float    red[128];         // 512 B
    // total ~152 KB -> 1 wg/CU

    const float* pR = W_hh + (size_t)j * HH;   // my row

    // ---- stage weights: words 0..63 -> 64 AGPRs
    unsigned wag[64];
    #pragma unroll
    for (int k = 0; k < 64; ++k) {
        unsigned p = packh2(pR[2 * k], pR[2 * k + 1]);
        AGPR_W(wag[k], p);
    }
    // ---- words 64..91 -> 28 arch VGPRs (opaque: no remat-from-global)
    unsigned wv[28];
    #pragma unroll
    for (int k = 0; k < 28; ++k)
        wv[k] = packh2(pR[2 * (64 + k)], pR[2 * (64 + k) + 1]);
    #pragma unroll
    for (int k = 0; k < 28; ++k)
        asm volatile("" : "+v"(wv[k]));
    // ---- words 92..127 -> LDS (9 uint4 blocks)
    #pragma unroll
    for (int blk = 0; blk < 9; ++blk) {
        #pragma unroll
        for (int u = 0; u < 4; ++u) {
            const int k = 2 * (92 + blk * 4 + u);
            wl[blk][j][u] = packh2(pR[k], pR[k + 1]);
        }
    }

    // per-row input weight + bias
    const float wih_r  = W_ih[j];
    const float bias_r = b_ih[j] + b_hh[j];

    // stage x; init h
    if (j < TT) x_lds[j] = x[(size_t)b * TT + j];
    if (j < 128) h_lds[j] = 0u;
    if (j < 256) h32[j] = 0.0f;
    float c = 0.0f;                   // cell state (threads 0..255, elem j)
    __syncthreads();

    for (int t = 0; t < TT; ++t) {
        const float xv = x_lds[t];
        const unsigned hv0 = h_lds[lane];        // h words 0..63 (lane l -> word l)
        const unsigned hv1 = h_lds[64 + lane];   // h words 64..127
        float acc0 = 0.f, acc1 = 0.f, acc2 = 0.f, acc3 = 0.f;

        // ---- words 0..63: AGPR weights, h via readlane(hv0)
        #pragma unroll
        for (int k = 0; k < 16; ++k) {
            unsigned w0, w1, w2, w3;
            AGPR_R(w0, wag[4*k+0]);
            AGPR_R(w1, wag[4*k+1]);
            AGPR_R(w2, wag[4*k+2]);
            AGPR_R(w3, wag[4*k+3]);
            acc0 = dot2acc(w0, HLANE(hv0, 4*k+0), acc0);
            acc1 = dot2acc(w1, HLANE(hv0, 4*k+1), acc1);
            acc2 = dot2acc(w2, HLANE(hv0, 4*k+2), acc2);
            acc3 = dot2acc(w3, HLANE(hv0, 4*k+3), acc3);
        }
        // ---- words 64..91: arch weights, h via readlane(hv1, 0..27)
        #pragma unroll
        for (int k = 0; k < 7; ++k) {
            acc0 = dot2acc(wv[4*k+0], HLANE(hv1, 4*k+0), acc0);
            acc1 = dot2acc(wv[4*k+1], HLANE(hv1, 4*k+1), acc1);
            acc2 = dot2acc(wv[4*k+2], HLANE(hv1, 4*k+2), acc2);
            acc3 = dot2acc(wv[4*k+3], HLANE(hv1, 4*k+3), acc3);
        }
        // ---- words 92..127: LDS tail weights, h via readlane(hv1, 28..63)
        #pragma unroll
        for (int blk = 0; blk < 9; ++blk) {
            uint4 wq = *reinterpret_cast<const uint4*>(&wl[blk][j][0]);
            acc0 = dot2acc(wq.x, HLANE(hv1, 28 + 4*blk+0), acc0);
            acc1 = dot2acc(wq.y, HLANE(hv1, 28 + 4*blk+1), acc1);
            acc2 = dot2acc(wq.z, HLANE(hv1, 28 + 4*blk+2), acc2);
            acc3 = dot2acc(wq.w, HLANE(hv1, 28 + 4*blk+3), acc3);
        }
        gates[j] = ((acc0 + acc1) + (acc2 + acc3))
                 + __builtin_fmaf(xv, wih_r, bias_r);
        __syncthreads();

        // ---- cell update: threads 0..255 (element j)
        if (j < 256) {
            float gi = gates[j];
            float gf = gates[256 + j];
            float gg = gates[512 + j];
            float go = gates[768 + j];
            gi = __builtin_amdgcn_rcpf(1.f + __expf(-gi));
            gf = __builtin_amdgcn_rcpf(1.f + __expf(-gf));
            go = __builtin_amdgcn_rcpf(1.f + __expf(-go));
            gg = 2.f * __builtin_amdgcn_rcpf(1.f + __expf(-2.f * gg)) - 1.f;
            c = __builtin_fmaf(gf, c, gi * gg);
            float th = 2.f * __builtin_amdgcn_rcpf(1.f + __expf(-2.f * c)) - 1.f;
            float hn = go * th;
            h32[j] = hn;
            reinterpret_cast<unsigned short*>(h_lds)[j] =
                __builtin_bit_cast(unsigned short, (_Float16)hn);
        }
        __syncthreads();
    }

    // ---- epilogue MLP: y = relu(h @ W1.T + b1) @ W2.T + b2
    if (j < 128) {
        const float4* w1p = reinterpret_cast<const float4*>(W1 + (size_t)j * HH);
        const float4* hp  = reinterpret_cast<const float4*>(h32);
        float s0 = 0.f, s1 = 0.f, s2 = 0.f, s3 = 0.f;
        #pragma unroll
        for (int k = 0; k < 64; ++k) {
            float4 wv4 = w1p[k], hv = hp[k];
            s0 = __builtin_fmaf(wv4.x, hv.x, s0);
            s1 = __builtin_fmaf(wv4.y, hv.y, s1);
            s2 = __builtin_fmaf(wv4.z, hv.z, s2);
            s3 = __builtin_fmaf(wv4.w, hv.w, s3);
        }
        float rv = fmaxf((s0 + s1) + (s2 + s3) + b1[j], 0.f);
        red[j] = rv * W2[j];
    }
    __syncthreads();
    if (j == 0) {
        float y = b2[0];
        #pragma unroll 4
        for (int k = 0; k < 128; ++k) y += red[k];
        out[b] = y;
    }
}

extern "C" void kernel_launch(void* const* d_in, const int* in_sizes, int n_in,
                              void* d_out, int out_size, void* d_ws, size_t ws_size,
                              hipStream_t stream) {
    const float* x    = (const float*)d_in[0];
    const float* W_ih = (const float*)d_in[1];
    const float* W_hh = (const float*)d_in[2];
    const float* b_ih = (const float*)d_in[3];
    const float* b_hh = (const float*)d_in[4];
    const float* W1   = (const float*)d_in[5];
    const float* b1   = (const float*)d_in[6];
    const float* W2   = (const float*)d_in[7];
    const float* b2   = (const float*)d_in[8];
    float* out = (float*)d_out;

    lstm_single<<<128, 1024, 0, stream>>>(x, W_ih, W_hh, b_ih, b_hh,
                                          W1, b1, W2, b2, out);
}

// Round 21
// 1171.824 us; speedup vs baseline: 1.2421x; 1.2421x over previous
//
#include <hip/hip_runtime.h>

#define TT 512
#define HH 256

typedef _Float16 half2t __attribute__((ext_vector_type(2)));

// fp16-pair dot with fp32 accumulate (v_dot2_f32_f16 when available).
__device__ __forceinline__ float dot2acc(unsigned w, unsigned h, float acc) {
#if __has_builtin(__builtin_amdgcn_fdot2)
    return __builtin_amdgcn_fdot2(__builtin_bit_cast(half2t, w),
                                  __builtin_bit_cast(half2t, h), acc, false);
#else
    union U { unsigned u; _Float16 f[2]; };
    U uw, uh; uw.u = w; uh.u = h;
    acc = __builtin_fmaf((float)uw.f[0], (float)uh.f[0], acc);
    acc = __builtin_fmaf((float)uw.f[1], (float)uh.f[1], acc);
    return acc;
#endif
}

__device__ __forceinline__ unsigned packh2(float a, float b) {
    union U { _Float16 f[2]; unsigned u; } r;
    r.f[0] = (_Float16)a; r.f[1] = (_Float16)b;   // RNE conversion
    return r.u;
}

#define AGPR_W(dst, src) \
    asm volatile("v_accvgpr_write_b32 %0, %1" : "=a"(dst) : "v"(src))
#define AGPR_R(dst, src) \
    asm("v_accvgpr_read_b32 %0, %1" : "=v"(dst) : "a"(src))

// 4-lane (quad) butterfly sum via DPP quad_perm -- pure VALU, no LDS.
// 0xB1 = quad_perm [1,0,3,2] (xor 1); 0x4E = quad_perm [2,3,0,1] (xor 2).
__device__ __forceinline__ float qsum4(float v) {
    int a = __builtin_amdgcn_mov_dpp(__builtin_bit_cast(int, v), 0xB1, 0xF, 0xF, true);
    float r = v + __builtin_bit_cast(float, a);
    int b = __builtin_amdgcn_mov_dpp(__builtin_bit_cast(int, r), 0x4E, 0xF, 0xF, true);
    return r + __builtin_bit_cast(float, b);
}

// C=1, 1024 threads/wg, one wg per batch (128 wgs, plain launch).
// TRANSPOSED layout (R21): thread = (element e = j>>2, K-chunk s = j&3).
// Thread holds rows {e, 256+e, 512+e, 768+e} x K[64s..64s+64) = 128 packed
// fp16 words (16 AGPR + 7 arch + 9 LDS per row). Per step: 128 dot2 into 4
// gate accumulators -> DPP quad butterfly (lanes s=0..3 of the quad) ->
// EVERY thread redundantly computes its element's cell -> single writer per
// quad (s == e>>6) publishes fp16 h to the double-buffered padded slice
// buffer (addr = w + 4*(w>>5): quad reads land on disjoint banks) ->
// ONE __syncthreads per step. Deleted vs R15-R20: second barrier, gates[]
// LDS roundtrip, idle-wave cell phase, 24/41 LDS ops per wave.
__global__ __launch_bounds__(1024)
__attribute__((amdgpu_waves_per_eu(4, 4)))
void lstm_single(
    const float* __restrict__ x,      // [B,T]
    const float* __restrict__ W_ih,   // [1024]
    const float* __restrict__ W_hh,   // [1024,256]
    const float* __restrict__ b_ih,   // [1024]
    const float* __restrict__ b_hh,   // [1024]
    const float* __restrict__ W1,     // [128,256]
    const float* __restrict__ b1,     // [128]
    const float* __restrict__ W2,     // [128]
    const float* __restrict__ b2,     // [1]
    float* __restrict__ out)          // [B]
{
    const int b = blockIdx.x;
    const int j = threadIdx.x;        // 0..1023
    const int e = j >> 2;             // element 0..255
    const int s = j & 3;              // K-chunk (64 fp32) 0..3

    __shared__ __align__(16) unsigned wl[9][1024][4]; // 144 KB weight tail
    __shared__ __align__(16) unsigned hbuf[2][140];   // h fp16 words, padded slices
    __shared__ float h32[HH];                         // 1 KB (epilogue)
    __shared__ float x_lds[TT];                       // 2 KB
    __shared__ float red[128];                        // 512 B
    // total ~148.6 KB -> 1 wg/CU

    // ---- stage weights: per row g: words 0..15 -> AGPR, 16..22 -> arch,
    //      23..31 -> LDS tail (m = g*9 + (k-23), packed as 9 uint4)
    unsigned wag[64];
    unsigned wv[28];
    #pragma unroll
    for (int g = 0; g < 4; ++g) {
        const float* pR = W_hh + (size_t)(g * 256 + e) * HH + 64 * s;
        #pragma unroll
        for (int k = 0; k < 16; ++k) {
            unsigned pw = packh2(pR[2 * k], pR[2 * k + 1]);
            AGPR_W(wag[g * 16 + k], pw);
        }
        #pragma unroll
        for (int k = 0; k < 7; ++k)
            wv[g * 7 + k] = packh2(pR[2 * (16 + k)], pR[2 * (16 + k) + 1]);
    }
    #pragma unroll
    for (int k = 0; k < 28; ++k)
        asm volatile("" : "+v"(wv[k]));
    #pragma unroll
    for (int u = 0; u < 9; ++u) {
        #pragma unroll
        for (int c2 = 0; c2 < 4; ++c2) {
            const int m = 4 * u + c2;            // 0..35
            const int g = m / 9, k = 23 + m % 9; // row, row-word
            const float* pR = W_hh + (size_t)(g * 256 + e) * HH + 64 * s;
            wl[u][j][c2] = packh2(pR[2 * k], pR[2 * k + 1]);
        }
    }

    // cell constants (all 4 quad lanes redundant)
    float wih[4], bias[4];
    #pragma unroll
    for (int g = 0; g < 4; ++g) {
        const int R = g * 256 + e;
        wih[g]  = W_ih[R];
        bias[g] = b_ih[R] + b_hh[R];
    }

    if (j < TT) x_lds[j] = x[(size_t)b * TT + j];
    if (j < 140) { hbuf[0][j] = 0u; hbuf[1][j] = 0u; }
    float c = 0.0f;                   // cell state of element e (quad-redundant)
    __syncthreads();

    for (int t = 0; t < TT; ++t) {
        const int p  = t & 1;
        const int pn = p ^ 1;
        const float xv = x_lds[t];
        // my h slice: words 32s..32s+31, stored at 36s..36s+31 (pad 4/slice)
        const unsigned* hb = &hbuf[p][36 * s];
        float acc[4] = {0.f, 0.f, 0.f, 0.f};

        // ---- row words 0..15 (AGPR): h blocks 0..3
        #pragma unroll
        for (int i = 0; i < 4; ++i) {
            uint4 hq = *reinterpret_cast<const uint4*>(&hb[4 * i]);
            #pragma unroll
            for (int g = 0; g < 4; ++g) {
                unsigned w0, w1, w2, w3;
                AGPR_R(w0, wag[g * 16 + 4 * i + 0]);
                AGPR_R(w1, wag[g * 16 + 4 * i + 1]);
                AGPR_R(w2, wag[g * 16 + 4 * i + 2]);
                AGPR_R(w3, wag[g * 16 + 4 * i + 3]);
                acc[g] = dot2acc(w0, hq.x, acc[g]);
                acc[g] = dot2acc(w1, hq.y, acc[g]);
                acc[g] = dot2acc(w2, hq.z, acc[g]);
                acc[g] = dot2acc(w3, hq.w, acc[g]);
            }
        }
        // ---- row words 16..22 (arch): h blocks 4,5 (word 23 used below)
        uint4 h4 = *reinterpret_cast<const uint4*>(&hb[16]);
        uint4 h5 = *reinterpret_cast<const uint4*>(&hb[20]);
        #pragma unroll
        for (int g = 0; g < 4; ++g) {
            acc[g] = dot2acc(wv[g * 7 + 0], h4.x, acc[g]);
            acc[g] = dot2acc(wv[g * 7 + 1], h4.y, acc[g]);
            acc[g] = dot2acc(wv[g * 7 + 2], h4.z, acc[g]);
            acc[g] = dot2acc(wv[g * 7 + 3], h4.w, acc[g]);
            acc[g] = dot2acc(wv[g * 7 + 4], h5.x, acc[g]);
            acc[g] = dot2acc(wv[g * 7 + 5], h5.y, acc[g]);
            acc[g] = dot2acc(wv[g * 7 + 6], h5.z, acc[g]);
        }
        // ---- row words 23..31 (LDS tail): h words 23..31
        uint4 h6 = *reinterpret_cast<const uint4*>(&hb[24]);
        uint4 h7 = *reinterpret_cast<const uint4*>(&hb[28]);
        const unsigned hw[9] = {h5.w, h6.x, h6.y, h6.z, h6.w,
                                h7.x, h7.y, h7.z, h7.w};
        #pragma unroll
        for (int u = 0; u < 9; ++u) {
            uint4 wq = *reinterpret_cast<const uint4*>(&wl[u][j][0]);
            { const int m = 4*u+0; acc[m/9] = dot2acc(wq.x, hw[m%9], acc[m/9]); }
            { const int m = 4*u+1; acc[m/9] = dot2acc(wq.y, hw[m%9], acc[m/9]); }
            { const int m = 4*u+2; acc[m/9] = dot2acc(wq.z, hw[m%9], acc[m/9]); }
            { const int m = 4*u+3; acc[m/9] = dot2acc(wq.w, hw[m%9], acc[m/9]); }
        }

        // ---- quad butterfly: all 4 lanes get full gate sums (pure VALU)
        float gi = qsum4(acc[0]) + __builtin_fmaf(xv, wih[0], bias[0]);
        float gf = qsum4(acc[1]) + __builtin_fmaf(xv, wih[1], bias[1]);
        float gg = qsum4(acc[2]) + __builtin_fmaf(xv, wih[2], bias[2]);
        float go = qsum4(acc[3]) + __builtin_fmaf(xv, wih[3], bias[3]);

        // ---- cell update (quad-redundant, no idle waves)
        gi = __builtin_amdgcn_rcpf(1.f + __expf(-gi));
        gf = __builtin_amdgcn_rcpf(1.f + __expf(-gf));
        go = __builtin_amdgcn_rcpf(1.f + __expf(-go));
        gg = 2.f * __builtin_amdgcn_rcpf(1.f + __expf(-2.f * gg)) - 1.f;
        c = __builtin_fmaf(gf, c, gi * gg);
        float th = 2.f * __builtin_amdgcn_rcpf(1.f + __expf(-2.f * c)) - 1.f;
        float hn = go * th;

        // ---- publish: one writer per quad (s == e>>6); ushort addr e + 8s
        if ((e >> 6) == s)
            reinterpret_cast<unsigned short*>(&hbuf[pn][0])[e + 8 * s] =
                __builtin_bit_cast(unsigned short, (_Float16)hn);
        if (s == 0) h32[e] = hn;
        __syncthreads();              // the ONLY barrier per step
    }

    // ---- epilogue MLP: y = relu(h @ W1.T + b1) @ W2.T + b2
    if (j < 128) {
        const float4* w1p = reinterpret_cast<const float4*>(W1 + (size_t)j * HH);
        const float4* hp  = reinterpret_cast<const float4*>(h32);
        float s0 = 0.f, s1 = 0.f, s2 = 0.f, s3 = 0.f;
        #pragma unroll
        for (int k = 0; k < 64; ++k) {
            float4 wv4 = w1p[k], hv = hp[k];
            s0 = __builtin_fmaf(wv4.x, hv.x, s0);
            s1 = __builtin_fmaf(wv4.y, hv.y, s1);
            s2 = __builtin_fmaf(wv4.z, hv.z, s2);
            s3 = __builtin_fmaf(wv4.w, hv.w, s3);
        }
        float rv = fmaxf((s0 + s1) + (s2 + s3) + b1[j], 0.f);
        red[j] = rv * W2[j];
    }
    __syncthreads();
    if (j == 0) {
        float y = b2[0];
        #pragma unroll 4
        for (int k = 0; k < 128; ++k) y += red[k];
        out[b] = y;
    }
}

extern "C" void kernel_launch(void* const* d_in, const int* in_sizes, int n_in,
                              void* d_out, int out_size, void* d_ws, size_t ws_size,
                              hipStream_t stream) {
    const float* x    = (const float*)d_in[0];
    const float* W_ih = (const float*)d_in[1];
    const float* W_hh = (const float*)d_in[2];
    const float* b_ih = (const float*)d_in[3];
    const float* b_hh = (const float*)d_in[4];
    const float* W1   = (const float*)d_in[5];
    const float* b1   = (const float*)d_in[6];
    const float* W2   = (const float*)d_in[7];
    const float* b2   = (const float*)d_in[8];
    float* out = (float*)d_out;

    lstm_single<<<128, 1024, 0, stream>>>(x, W_ih, W_hh, b_ih, b_hh,
                                          W1, b1, W2, b2, out);
}